// Round 8
// baseline (481.634 us; speedup 1.0000x reference)
//
#include <hip/hip_runtime.h>
#include <hip/hip_bf16.h>

// 2-layer GCN, N=100000, E=1200000, dims 64, fp32 in/out.
//
// R18: machine-fill fixes (launch-bubble theory was falsified in R16/17).
// (1) k_fagg: dynamic work-stealing over the 3136 32-slot units via a
//     global counter; grid=2048 (= co-resident capacity at 4 waves x
//     48 VGPR) -> no 1.53-pass drain, no static-assignment tail.
// (2) GEMM1 decoupled from CSR: k_part also builds per-node degrees
//     (ndeg, 1 global atomicAdd/edge); GEMM1 tiles need only
//     rsqrtf(ndeg[row]+1) (bit-identical to CSR dinv). k_csr launches
//     1024 blocks: 0..195 run the CSR phase then join a per-wave
//     work-stealing pool over the 6250 GEMM tiles; 196+ steal
//     immediately -> GEMM1 overlaps CSR on the full machine.
// Everything else (R15 fagg body: 2-deep ping-pong gathers, degree-
// balanced slots; R15 part/Wpack) unchanged. absmax 0.00390625.

#define FEAT 64
#define CAP 9216

typedef __attribute__((ext_vector_type(8))) short bf16x8;
typedef __attribute__((ext_vector_type(4))) float f32x4;
union BF8 { bf16x8 v; unsigned short u[8]; unsigned pk[4]; uint4 q; };

__device__ __forceinline__ unsigned short f2bf(float f) {
    unsigned u = __float_as_uint(f);
    return (unsigned short)((u + 0x7FFFu + ((u >> 16) & 1u)) >> 16);   // RNE
}
__device__ __forceinline__ float bflo(unsigned u) { return __uint_as_float(u << 16); }
__device__ __forceinline__ float bfhi(unsigned u) { return __uint_as_float(u & 0xFFFF0000u); }
__device__ __forceinline__ unsigned pk2bf(float a, float b) {   // v_cvt_pk_bf16_f32
    union { __hip_bfloat162 b; unsigned u; } cv;
    cv.b = __float22bfloat162_rn(make_float2(a, b));
    return cv.u;
}

// ---- partition edges into fixed-capacity buckets (src<<9 | dst&511)
// + per-node degree histogram (ndeg); tail blocks pack W (column-permuted).
__global__ void __launch_bounds__(256)
k_part(const int* __restrict__ src, const int* __restrict__ dst,
       int* __restrict__ bcnt, int* __restrict__ ndeg,
       unsigned* __restrict__ buckets, int E, int pblocks,
       const float* __restrict__ W1, const float* __restrict__ W2,
       const float* __restrict__ Wl, unsigned short* __restrict__ P) {
    if ((int)blockIdx.x >= pblocks) {
        int widx = blockIdx.x - pblocks;
        const float* W = (widx == 0) ? W1 : (widx == 1) ? W2 : Wl;
        unsigned short* p = P + widx * 4096;
        for (int i = threadIdx.x; i < 4096; i += 256) {
            int c = i >> 10, s = (i >> 9) & 1, l = (i >> 3) & 63, j = i & 7;
            int k = s * 32 + ((l >> 4) << 3) + j;
            int col = ((l & 15) << 2) + c;      // lane m -> output cols 4m..4m+3
            p[i] = f2bf(W[k * 64 + col]);
        }
        return;
    }
    __shared__ unsigned pk[4096];
    __shared__ unsigned char bk[4096];
    __shared__ int h[256];
    __shared__ int cur[256];
    int tid = threadIdx.x;
    h[tid] = 0;
    __syncthreads();
    int base = blockIdx.x * 4096;
#pragma unroll
    for (int i = 0; i < 16; ++i) {
        int li = i * 256 + tid;
        int e = base + li;
        if (e < E) {
            int s = src[e], d = dst[e];
            int b = d >> 9;
            pk[li] = ((unsigned)s << 9) | ((unsigned)d & 511u);
            bk[li] = (unsigned char)b;
            atomicAdd(&h[b], 1);
            atomicAdd(&ndeg[d], 1);             // per-node degree (for GEMM1 dinv)
        } else {
            bk[li] = 255;
        }
    }
    __syncthreads();
    {
        int c = h[tid];
        int run = c ? atomicAdd(&bcnt[tid], c) : 0;   // reserve [run, run+c)
        cur[tid] = run;
    }
    __syncthreads();
#pragma unroll
    for (int i = 0; i < 16; ++i) {
        int li = i * 256 + tid;
        int e = base + li;
        if (e < E) {
            int b = bk[li];
            int pos = atomicAdd(&cur[b], 1);
            buckets[(size_t)b * CAP + pos] = pk[li];
        }
    }
}

// ---- per-bucket CSR finish + degree counting-sort (blocks < NB), then ALL
// blocks work-steal layer-1 GEMM tiles: Hs1[16 rows] = (x@W1)*rsqrt(ndeg+1).
__global__ void __launch_bounds__(512)
k_csr(const unsigned* __restrict__ buckets, const int* __restrict__ bcnt,
      const int* __restrict__ ndeg, int* __restrict__ gctr,
      const float* __restrict__ x, const unsigned short* __restrict__ Wpk,
      unsigned short* __restrict__ Hs1, int* __restrict__ esrc,
      int* __restrict__ perm, int2* __restrict__ pofs, float* __restrict__ pdinv,
      int n, int nb, int ntiles) {
    __shared__ int hist[512];
    __shared__ int cur[512];
    __shared__ int dh[64];
    __shared__ int dbase[64];
    __shared__ int dcur[64];
    int tid = threadIdx.x;
    int b = blockIdx.x;
    if (b < nb) {
        hist[tid] = 0;
        if (tid < 64) dh[tid] = 0;
        __syncthreads();
        int cnt = bcnt[b];
        size_t beg = (size_t)b * CAP;
        for (int j = tid; j < cnt; j += 512)
            atomicAdd(&hist[buckets[beg + j] & 511u], 1);
        __syncthreads();
        int v = hist[tid];
        for (int off = 1; off < 512; off <<= 1) {        // inclusive scan
            int xs = (tid >= off) ? hist[tid - off] : 0;
            __syncthreads();
            hist[tid] += xs;
            __syncthreads();
        }
        int excl = hist[tid] - v;
        int node = (b << 9) + tid;
        bool valid = node < n;
        if (valid) atomicAdd(&dh[min(v, 63)], 1);
        cur[tid] = excl;
        __syncthreads();
        if (tid == 0) {
            int run = 0;
            for (int i = 0; i < 64; ++i) { dbase[i] = run; run += dh[i]; dcur[i] = 0; }
        }
        __syncthreads();
        if (valid) {
            int bin = min(v, 63);
            int r = atomicAdd(&dcur[bin], 1);
            int gs = (b << 9) + dbase[bin] + r;          // compacted: slot<n iff valid
            perm[gs] = node;
            pofs[gs] = make_int2((int)beg + excl, (int)beg + excl + v);
            pdinv[gs] = rsqrtf((float)v + 1.0f);
        }
        for (int j = tid; j < cnt; j += 512) {
            unsigned u = buckets[beg + j];
            int loc = (int)(u & 511u);
            int r = atomicAdd(&cur[loc], 1);
            esrc[beg + r] = (int)(u >> 9);
        }
    }
    // ---- work-steal layer-1 GEMM tiles (independent of CSR phase) ----
    int lane = tid & 63;
    BF8 bfr[8];
    const uint4* wp = (const uint4*)Wpk;
#pragma unroll
    for (int f = 0; f < 8; ++f) bfr[f].q = wp[f * 64 + lane];
    int mrow = lane & 15, kq = lane >> 4, colb = lane & 15;
    for (;;) {
        int t;
        if (lane == 0) t = atomicAdd(gctr, 1);
        t = __shfl(t, 0);
        if (t >= ntiles) break;
        int rb = t << 4;
        int row = rb + mrow;
        bool ok = row < n;
        BF8 a0, a1;
        const float4* xr = (const float4*)(x + ((unsigned)row << 6));
        float4 z = make_float4(0.f, 0.f, 0.f, 0.f);
        float4 p0 = ok ? xr[kq * 2]     : z;
        float4 p1 = ok ? xr[kq * 2 + 1] : z;
        float4 p2 = ok ? xr[8 + kq * 2] : z;
        float4 p3 = ok ? xr[8 + kq * 2 + 1] : z;
        a0.pk[0] = pk2bf(p0.x, p0.y); a0.pk[1] = pk2bf(p0.z, p0.w);
        a0.pk[2] = pk2bf(p1.x, p1.y); a0.pk[3] = pk2bf(p1.z, p1.w);
        a1.pk[0] = pk2bf(p2.x, p2.y); a1.pk[1] = pk2bf(p2.z, p2.w);
        a1.pk[2] = pk2bf(p3.x, p3.y); a1.pk[3] = pk2bf(p3.z, p3.w);
        f32x4 acc0 = {0.f, 0.f, 0.f, 0.f}, acc1 = acc0, acc2 = acc0, acc3 = acc0;
        acc0 = __builtin_amdgcn_mfma_f32_16x16x32_bf16(a0.v, bfr[0].v, acc0, 0, 0, 0);
        acc0 = __builtin_amdgcn_mfma_f32_16x16x32_bf16(a1.v, bfr[1].v, acc0, 0, 0, 0);
        acc1 = __builtin_amdgcn_mfma_f32_16x16x32_bf16(a0.v, bfr[2].v, acc1, 0, 0, 0);
        acc1 = __builtin_amdgcn_mfma_f32_16x16x32_bf16(a1.v, bfr[3].v, acc1, 0, 0, 0);
        acc2 = __builtin_amdgcn_mfma_f32_16x16x32_bf16(a0.v, bfr[4].v, acc2, 0, 0, 0);
        acc2 = __builtin_amdgcn_mfma_f32_16x16x32_bf16(a1.v, bfr[5].v, acc2, 0, 0, 0);
        acc3 = __builtin_amdgcn_mfma_f32_16x16x32_bf16(a0.v, bfr[6].v, acc3, 0, 0, 0);
        acc3 = __builtin_amdgcn_mfma_f32_16x16x32_bf16(a1.v, bfr[7].v, acc3, 0, 0, 0);
        int rowb = rb + (kq << 2);
#pragma unroll
        for (int i = 0; i < 4; ++i) {
            if (rowb + i >= n) break;
            float sc = rsqrtf((float)ndeg[rowb + i] + 1.0f);   // == CSR dinv, bit-identical
            unsigned ro = (unsigned)(rowb + i) << 6;
            uint2 o = make_uint2(pk2bf(acc0[i] * sc, acc1[i] * sc),
                                 pk2bf(acc2[i] * sc, acc3[i] * sc));
            *(uint2*)(Hs1 + ro + (colb << 2)) = o;
        }
    }
}

// slot id for (bucket q, block-in-bucket B, local row r):
// wave (r>>3) draws from degree-quarter (r>>3); 8 consecutive sorted slots.
__device__ __forceinline__ int slot_of(int q, int B, int r) {
    return (q << 9) + ((r >> 3) << 7) + (B << 3) + (r & 7);
}

#define ACC8(H, W) \
    a0 = fmaf(bflo(H.x), W, a0); a1 = fmaf(bfhi(H.x), W, a1); \
    a2 = fmaf(bflo(H.y), W, a2); a3 = fmaf(bfhi(H.y), W, a3); \
    a4 = fmaf(bflo(H.z), W, a4); a5 = fmaf(bfhi(H.z), W, a5); \
    a6 = fmaf(bflo(H.w), W, a6); a7 = fmaf(bfhi(H.w), W, a7);

#define GROW(s) (*(const uint4*)(Hs + ((unsigned)(s) << 6) + (h8 << 3)))

#define HALF(hX0, hX1, hX2, hX3, sX0, sX1, sX2, sX3, wX0, wX1, wX2, wX3)  \
    {                                                                     \
        int jn = j + 8;                                                   \
        int n0 = sX0, n1 = sX1, n2 = sX2, n3 = sX3;                       \
        float v0 = 0.f, v1 = 0.f, v2 = 0.f, v3 = 0.f;                     \
        if (jn     < end) { n0 = esrc[jn];     v0 = 1.f; }                \
        if (jn + 1 < end) { n1 = esrc[jn + 1]; v1 = 1.f; }                \
        if (jn + 2 < end) { n2 = esrc[jn + 2]; v2 = 1.f; }                \
        if (jn + 3 < end) { n3 = esrc[jn + 3]; v3 = 1.f; }                \
        ACC8(hX0, wX0) ACC8(hX1, wX1) ACC8(hX2, wX2) ACC8(hX3, wX3)       \
        hX0 = GROW(n0); hX1 = GROW(n1); hX2 = GROW(n2); hX3 = GROW(n3);   \
        sX0 = n0; sX1 = n1; sX2 = n2; sX3 = n3;                           \
        wX0 = v0; wX1 = v1; wX2 = v2; wX3 = v3;                           \
        j += 4;                                                           \
    }

// ---- FUSED aggregation + GEMM with dynamic work-stealing over units.
// Unit = (bucket q, block-in-bucket B) -> 32 slots. Per unit:
// Phase 1: 8 slots/wave x 8 lanes, degree-balanced slot map, 2-deep
// ping-pong gather pipeline, weight-0 fmaf masking, register accumulation.
// Phase 2: LDS transpose (XOR swizzle) -> 4 MFMAs/wave; bf16 (*pdinv) or
// fp32 (+bias2) output scattered via perm.
template <bool RELU, bool OUT_F32>
__global__ void __launch_bounds__(256)
k_fagg(const int* __restrict__ perm, const int2* __restrict__ pofs,
       const float* __restrict__ pdinv, const int* __restrict__ esrc,
       const unsigned short* __restrict__ Hs, const float* __restrict__ bias1,
       const unsigned short* __restrict__ Wpk, const float* __restrict__ bias2,
       void* __restrict__ outv, int* __restrict__ ctr, int nunits, int n) {
    __shared__ uint4 lds_a[32][8];
    __shared__ int s_unit;
    int tid = threadIdx.x;
    int lane = tid & 63;
    int wv = tid >> 6;
    int h8 = lane & 7;
    int rl = (wv << 3) + (lane >> 3);            // local row 0..31
    for (;;) {
        if (tid == 0) s_unit = atomicAdd(ctr, 1);
        __syncthreads();                         // s_unit visible; lds_a safe to rewrite
        int unit = s_unit;
        if (unit >= nunits) break;               // uniform exit
        int q = unit >> 4, B = unit & 15;
        int slot = slot_of(q, B, rl);
        bool ok = slot < n;
        int node = 0, beg = 0, end = 0;
        float dd = 0.f;
        if (ok) {
            node = perm[slot];
            int2 oe = pofs[slot];
            beg = oe.x; end = oe.y;
            dd = pdinv[slot];
        }
        float a0 = 0.f, a1 = 0.f, a2 = 0.f, a3 = 0.f, a4 = 0.f, a5 = 0.f, a6 = 0.f, a7 = 0.f;
        {
            int j = beg;
            int sA0 = 0, sA1 = 0, sA2 = 0, sA3 = 0;
            float wA0 = 0.f, wA1 = 0.f, wA2 = 0.f, wA3 = 0.f;
            if (j     < end) { sA0 = esrc[j];     wA0 = 1.f; }
            if (j + 1 < end) { sA1 = esrc[j + 1]; wA1 = 1.f; }
            if (j + 2 < end) { sA2 = esrc[j + 2]; wA2 = 1.f; }
            if (j + 3 < end) { sA3 = esrc[j + 3]; wA3 = 1.f; }
            int sB0 = sA0, sB1 = sA1, sB2 = sA2, sB3 = sA3;
            float wB0 = 0.f, wB1 = 0.f, wB2 = 0.f, wB3 = 0.f;
            if (j + 4 < end) { sB0 = esrc[j + 4]; wB0 = 1.f; }
            if (j + 5 < end) { sB1 = esrc[j + 5]; wB1 = 1.f; }
            if (j + 6 < end) { sB2 = esrc[j + 6]; wB2 = 1.f; }
            if (j + 7 < end) { sB3 = esrc[j + 7]; wB3 = 1.f; }
            uint4 hA0 = GROW(sA0), hA1 = GROW(sA1), hA2 = GROW(sA2), hA3 = GROW(sA3);
            uint4 hB0 = GROW(sB0), hB1 = GROW(sB1), hB2 = GROW(sB2), hB3 = GROW(sB3);
            while (__ballot(j < end)) {
                HALF(hA0, hA1, hA2, hA3, sA0, sA1, sA2, sA3, wA0, wA1, wA2, wA3)
                if (!__ballot(j < end)) break;
                HALF(hB0, hB1, hB2, hB3, sB0, sB1, sB2, sB3, wB0, wB1, wB2, wB3)
            }
        }
        uint4 packed = make_uint4(0, 0, 0, 0);
        if (ok) {
            uint4 sv = *(const uint4*)(Hs + ((unsigned)node << 6) + (h8 << 3));
            const float4* b4 = (const float4*)bias1;
            float4 bA = b4[h8 * 2], bB = b4[h8 * 2 + 1];
            float r0 = (a0 + bflo(sv.x)) * dd + bA.x;
            float r1 = (a1 + bfhi(sv.x)) * dd + bA.y;
            float r2 = (a2 + bflo(sv.y)) * dd + bA.z;
            float r3 = (a3 + bfhi(sv.y)) * dd + bA.w;
            float r4 = (a4 + bflo(sv.z)) * dd + bB.x;
            float r5 = (a5 + bfhi(sv.z)) * dd + bB.y;
            float r6 = (a6 + bflo(sv.w)) * dd + bB.z;
            float r7 = (a7 + bfhi(sv.w)) * dd + bB.w;
            if (RELU) {
                r0 = fmaxf(r0, 0.f); r1 = fmaxf(r1, 0.f); r2 = fmaxf(r2, 0.f); r3 = fmaxf(r3, 0.f);
                r4 = fmaxf(r4, 0.f); r5 = fmaxf(r5, 0.f); r6 = fmaxf(r6, 0.f); r7 = fmaxf(r7, 0.f);
            }
            packed = make_uint4(pk2bf(r0, r1), pk2bf(r2, r3), pk2bf(r4, r5), pk2bf(r6, r7));
        }
        lds_a[rl][h8 ^ (rl & 7)] = packed;          // XOR swizzle: banks spread
        __syncthreads();
        // ---- phase 2: GEMM on the unit's 32 rows ----
        int hh = wv & 1, tt = wv >> 1;
        BF8 bq0, bq1, bq2, bq3;
        {
            const uint4* wp = (const uint4*)Wpk;
            bq0.q = wp[(4 * hh + 0) * 64 + lane];
            bq1.q = wp[(4 * hh + 1) * 64 + lane];
            bq2.q = wp[(4 * hh + 2) * 64 + lane];
            bq3.q = wp[(4 * hh + 3) * 64 + lane];
        }
        int mr = lane & 15, kq = lane >> 4, colb = lane & 15;
        int rloc = tt * 16 + mr;
        BF8 fa0, fa1;
        fa0.q = lds_a[rloc][kq ^ (rloc & 7)];
        fa1.q = lds_a[rloc][(kq + 4) ^ (rloc & 7)];
        f32x4 accA = {0.f, 0.f, 0.f, 0.f}, accB = accA;
        accA = __builtin_amdgcn_mfma_f32_16x16x32_bf16(fa0.v, bq0.v, accA, 0, 0, 0);
        accA = __builtin_amdgcn_mfma_f32_16x16x32_bf16(fa1.v, bq1.v, accA, 0, 0, 0);
        accB = __builtin_amdgcn_mfma_f32_16x16x32_bf16(fa0.v, bq2.v, accB, 0, 0, 0);
        accB = __builtin_amdgcn_mfma_f32_16x16x32_bf16(fa1.v, bq3.v, accB, 0, 0, 0);
        float b2x = 0.f, b2y = 0.f;
        if (OUT_F32) {
            b2x = bias2[(colb << 2) + (hh << 1)];
            b2y = bias2[(colb << 2) + (hh << 1) + 1];
        }
        int rowb = tt * 16 + (kq << 2);
#pragma unroll
        for (int i = 0; i < 4; ++i) {
            int sl = slot_of(q, B, rowb + i);
            if (sl >= n) continue;
            int orow = perm[sl];
            if (OUT_F32) {
                float2 o = make_float2(accA[i] + b2x, accB[i] + b2y);
                *(float2*)((float*)outv + ((unsigned)orow << 6) + (colb << 2) + (hh << 1)) = o;
            } else {
                float sc = pdinv[sl];
                unsigned o = pk2bf(accA[i] * sc, accB[i] * sc);
                *(unsigned*)((unsigned short*)outv + ((unsigned)orow << 6) + (colb << 2) + (hh << 1)) = o;
            }
        }
        // loop back: top-of-loop barrier orders next lds_a/s_unit writes
        // after this iteration's reads.
    }
}

extern "C" void kernel_launch(void* const* d_in, const int* in_sizes, int n_in,
                              void* d_out, int out_size, void* d_ws, size_t ws_size,
                              hipStream_t stream) {
    const float* x  = (const float*)d_in[0];
    const int*   ei = (const int*)d_in[1];   // [2][E] int32
    const float* W1 = (const float*)d_in[2];
    const float* b1 = (const float*)d_in[3];
    const float* W2 = (const float*)d_in[4];
    const float* b2 = (const float*)d_in[5];
    const float* Wl = (const float*)d_in[6];
    const float* bl = (const float*)d_in[7];
    float* out = (float*)d_out;

    const int n = in_sizes[0] / FEAT;   // 100000
    const int E = in_sizes[1] / 2;      // 1200000
    const int* src = ei;
    const int* dst = ei + E;

    const int B = 256;
    const int NB = (n + 511) >> 9;            // 196 buckets
    const int pblocks = (E + 4095) / 4096;
    const int nunits = NB * 16;               // 3136 32-slot units
    const int ntiles = (n + 15) >> 4;         // 6250 GEMM1 row-tiles

    char* w = (char*)d_ws;
    // zeroed region: bcnt(256) | ctrs(4) | ndeg(n)
    int*   bcnt     = (int*)w;
    int*   ctrs     = bcnt + 256;             // [0]=gemm1 [1]=fagg1 [2]=fagg2
    int*   ndeg     = bcnt + 260;
    size_t zwords   = 260 + (size_t)n;
    w += zwords * 4;
    float* pdinv    = (float*)w;            w += (size_t)n * 4;
    int*   perm     = (int*)w;              w += (size_t)n * 4;
    w = (char*)(((uintptr_t)w + 15) & ~(uintptr_t)15);
    int2*  pofs     = (int2*)w;             w += (size_t)n * 8;
    unsigned short* Wpk = (unsigned short*)w;  w += 3 * 4096 * 2;
    w = (char*)(((uintptr_t)w + 15) & ~(uintptr_t)15);
    unsigned* buckets = (unsigned*)w;       w += (size_t)NB * CAP * 4;
    int*   esrc     = (int*)w;              w += (size_t)NB * CAP * 4;
    unsigned short* bufA = (unsigned short*)w;  w += (size_t)n * FEAT * 2;  // Hs1
    unsigned short* bufB = (unsigned short*)w;                              // Hs3

    // ---- zero bcnt + counters + ndeg ----
    hipMemsetAsync(bcnt, 0, zwords * 4, stream);

    // ---- CSR scatter (+ per-node degrees + W pack) ----
    k_part<<<dim3(pblocks + 3), dim3(B), 0, stream>>>(src, dst, bcnt, ndeg,
                                                      buckets, E, pblocks,
                                                      W1, W2, Wl, Wpk);

    // ---- CSR finish + work-stolen layer-1 GEMM (full machine) ----
    k_csr<<<dim3(1024), dim3(512), 0, stream>>>(buckets, bcnt, ndeg, &ctrs[0],
                                                x, Wpk, bufA, esrc,
                                                perm, pofs, pdinv, n, NB, ntiles);

    // ---- fused layer-1 agg + layer-2 GEMM (work-stealing) ----
    k_fagg<true, false><<<dim3(2048), dim3(B), 0, stream>>>(
        perm, pofs, pdinv, esrc, bufA, b1, Wpk + 4096, nullptr, bufB,
        &ctrs[1], nunits, n);

    // ---- fused layer-2 agg + final linear (work-stealing) ----
    k_fagg<false, true><<<dim3(2048), dim3(B), 0, stream>>>(
        perm, pofs, pdinv, esrc, bufB, b2, Wpk + 8192, bl, out,
        &ctrs[2], nunits, n);
}

// Round 9
// 203.122 us; speedup vs baseline: 2.3712x; 2.3712x over previous
//
#include <hip/hip_runtime.h>
#include <hip/hip_bf16.h>

// 2-layer GCN, N=100000, E=1200000, dims 64, fp32 in/out.
//
// R19 = R17 (proven 205us) + one atomic-free fagg scheduling fix.
// R18's work-stealing regressed 2.3x: same-address global atomicAdd
// serializes at ~25ns/op -> 14.4K grabs = 176us of counter service.
// LESSON: ticket counters hand out <= ~40M grabs/s; never steal at
// sub-us work granularity.
// R19 fagg remap: block = 32 CONSECUTIVE degree-sorted slots (all 4
// waves in the same degree region -> the LDS-transpose barrier no longer
// pays max-over-quarters, ~40% block-time inflation removed) + heavy-
// first dispatch (q = blk % NB, L = 15 - blk/NB -> LPT packing under HW
// refill). Zero atomics. Per-node edge order unchanged -> absmax
// 0.00390625. k_part/k_csr(+fused GEMM1) byte-identical to R17.

#define FEAT 64
#define CAP 9216

typedef __attribute__((ext_vector_type(8))) short bf16x8;
typedef __attribute__((ext_vector_type(4))) float f32x4;
union BF8 { bf16x8 v; unsigned short u[8]; unsigned pk[4]; uint4 q; };

__device__ __forceinline__ unsigned short f2bf(float f) {
    unsigned u = __float_as_uint(f);
    return (unsigned short)((u + 0x7FFFu + ((u >> 16) & 1u)) >> 16);   // RNE
}
__device__ __forceinline__ float bflo(unsigned u) { return __uint_as_float(u << 16); }
__device__ __forceinline__ float bfhi(unsigned u) { return __uint_as_float(u & 0xFFFF0000u); }
__device__ __forceinline__ unsigned pk2bf(float a, float b) {   // v_cvt_pk_bf16_f32
    union { __hip_bfloat162 b; unsigned u; } cv;
    cv.b = __float22bfloat162_rn(make_float2(a, b));
    return cv.u;
}

// ---- partition edges into fixed-capacity buckets (src<<9 | dst&511);
// tail blocks pack W into MFMA B-frag layout (column-permuted).
__global__ void __launch_bounds__(256)
k_part(const int* __restrict__ src, const int* __restrict__ dst,
       int* __restrict__ bcnt, unsigned* __restrict__ buckets, int E, int pblocks,
       const float* __restrict__ W1, const float* __restrict__ W2,
       const float* __restrict__ Wl, unsigned short* __restrict__ P) {
    if ((int)blockIdx.x >= pblocks) {
        int widx = blockIdx.x - pblocks;
        const float* W = (widx == 0) ? W1 : (widx == 1) ? W2 : Wl;
        unsigned short* p = P + widx * 4096;
        for (int i = threadIdx.x; i < 4096; i += 256) {
            int c = i >> 10, s = (i >> 9) & 1, l = (i >> 3) & 63, j = i & 7;
            int k = s * 32 + ((l >> 4) << 3) + j;
            int col = ((l & 15) << 2) + c;      // lane m -> output cols 4m..4m+3
            p[i] = f2bf(W[k * 64 + col]);
        }
        return;
    }
    __shared__ unsigned pk[4096];
    __shared__ unsigned char bk[4096];
    __shared__ int h[256];
    __shared__ int cur[256];
    int tid = threadIdx.x;
    h[tid] = 0;
    __syncthreads();
    int base = blockIdx.x * 4096;
#pragma unroll
    for (int i = 0; i < 16; ++i) {
        int li = i * 256 + tid;
        int e = base + li;
        if (e < E) {
            int s = src[e], d = dst[e];
            int b = d >> 9;
            pk[li] = ((unsigned)s << 9) | ((unsigned)d & 511u);
            bk[li] = (unsigned char)b;
            atomicAdd(&h[b], 1);
        } else {
            bk[li] = 255;
        }
    }
    __syncthreads();
    {
        int c = h[tid];
        int run = c ? atomicAdd(&bcnt[tid], c) : 0;   // reserve [run, run+c)
        cur[tid] = run;
    }
    __syncthreads();
#pragma unroll
    for (int i = 0; i < 16; ++i) {
        int li = i * 256 + tid;
        int e = base + li;
        if (e < E) {
            int b = bk[li];
            int pos = atomicAdd(&cur[b], 1);
            buckets[(size_t)b * CAP + pos] = pk[li];
        }
    }
}

// ---- per-bucket CSR finish + degree counting-sort + FUSED layer-1 GEMM.
// CSR: node hist -> scan -> degree-sort -> perm/pofs/pdinv + esrc scatter.
// GEMM tail: Hs1[row] = (x[row]@W1)*dinv[row] for the bucket's 512 rows
// (8 waves x 4 tiles of 16 rows; dinv via LDS sdinv).
__global__ void __launch_bounds__(512)
k_csr(const unsigned* __restrict__ buckets, const int* __restrict__ bcnt,
      const float* __restrict__ x, const unsigned short* __restrict__ Wpk,
      unsigned short* __restrict__ Hs1, int* __restrict__ esrc,
      int* __restrict__ perm, int2* __restrict__ pofs, float* __restrict__ pdinv,
      int n) {
    __shared__ int hist[512];
    __shared__ int cur[512];
    __shared__ int dh[64];
    __shared__ int dbase[64];
    __shared__ int dcur[64];
    __shared__ float sdinv[512];
    int tid = threadIdx.x;
    int b = blockIdx.x;
    hist[tid] = 0;
    if (tid < 64) dh[tid] = 0;
    __syncthreads();
    int cnt = bcnt[b];
    size_t beg = (size_t)b * CAP;
    for (int j = tid; j < cnt; j += 512)
        atomicAdd(&hist[buckets[beg + j] & 511u], 1);
    __syncthreads();
    int v = hist[tid];
    for (int off = 1; off < 512; off <<= 1) {        // inclusive scan
        int xs = (tid >= off) ? hist[tid - off] : 0;
        __syncthreads();
        hist[tid] += xs;
        __syncthreads();
    }
    int excl = hist[tid] - v;
    int node = (b << 9) + tid;
    bool valid = node < n;
    float di = rsqrtf((float)v + 1.0f);
    sdinv[tid] = di;
    if (valid) atomicAdd(&dh[min(v, 63)], 1);
    cur[tid] = excl;
    __syncthreads();
    if (tid == 0) {
        int run = 0;
        for (int i = 0; i < 64; ++i) { dbase[i] = run; run += dh[i]; dcur[i] = 0; }
    }
    __syncthreads();
    if (valid) {
        int bin = min(v, 63);
        int r = atomicAdd(&dcur[bin], 1);
        int gs = (b << 9) + dbase[bin] + r;          // compacted: slot<n iff valid
        perm[gs] = node;
        pofs[gs] = make_int2((int)beg + excl, (int)beg + excl + v);
        pdinv[gs] = di;
    }
    for (int j = tid; j < cnt; j += 512) {
        unsigned u = buckets[beg + j];
        int loc = (int)(u & 511u);
        int r = atomicAdd(&cur[loc], 1);
        esrc[beg + r] = (int)(u >> 9);
    }
    // ---- fused layer-1 GEMM (sdinv synced by the barriers above) ----
    int lane = tid & 63;
    int wv = tid >> 6;
    BF8 bfr[8];
    const uint4* wp = (const uint4*)Wpk;
#pragma unroll
    for (int f = 0; f < 8; ++f) bfr[f].q = wp[f * 64 + lane];
    int mrow = lane & 15, kq = lane >> 4, colb = lane & 15;
    for (int t = wv; t < 32; t += 8) {
        int rb = (b << 9) + (t << 4);
        int row = rb + mrow;
        bool ok = row < n;
        BF8 a0, a1;
        const float4* xr = (const float4*)(x + ((unsigned)row << 6));
        float4 z = make_float4(0.f, 0.f, 0.f, 0.f);
        float4 p0 = ok ? xr[kq * 2]     : z;
        float4 p1 = ok ? xr[kq * 2 + 1] : z;
        float4 p2 = ok ? xr[8 + kq * 2] : z;
        float4 p3 = ok ? xr[8 + kq * 2 + 1] : z;
        a0.pk[0] = pk2bf(p0.x, p0.y); a0.pk[1] = pk2bf(p0.z, p0.w);
        a0.pk[2] = pk2bf(p1.x, p1.y); a0.pk[3] = pk2bf(p1.z, p1.w);
        a1.pk[0] = pk2bf(p2.x, p2.y); a1.pk[1] = pk2bf(p2.z, p2.w);
        a1.pk[2] = pk2bf(p3.x, p3.y); a1.pk[3] = pk2bf(p3.z, p3.w);
        f32x4 acc0 = {0.f, 0.f, 0.f, 0.f}, acc1 = acc0, acc2 = acc0, acc3 = acc0;
        acc0 = __builtin_amdgcn_mfma_f32_16x16x32_bf16(a0.v, bfr[0].v, acc0, 0, 0, 0);
        acc0 = __builtin_amdgcn_mfma_f32_16x16x32_bf16(a1.v, bfr[1].v, acc0, 0, 0, 0);
        acc1 = __builtin_amdgcn_mfma_f32_16x16x32_bf16(a0.v, bfr[2].v, acc1, 0, 0, 0);
        acc1 = __builtin_amdgcn_mfma_f32_16x16x32_bf16(a1.v, bfr[3].v, acc1, 0, 0, 0);
        acc2 = __builtin_amdgcn_mfma_f32_16x16x32_bf16(a0.v, bfr[4].v, acc2, 0, 0, 0);
        acc2 = __builtin_amdgcn_mfma_f32_16x16x32_bf16(a1.v, bfr[5].v, acc2, 0, 0, 0);
        acc3 = __builtin_amdgcn_mfma_f32_16x16x32_bf16(a0.v, bfr[6].v, acc3, 0, 0, 0);
        acc3 = __builtin_amdgcn_mfma_f32_16x16x32_bf16(a1.v, bfr[7].v, acc3, 0, 0, 0);
        int rowb = rb + (kq << 2);
        int lrow = (t << 4) + (kq << 2);
#pragma unroll
        for (int i = 0; i < 4; ++i) {
            if (rowb + i >= n) break;
            float sc = sdinv[lrow + i];
            unsigned ro = (unsigned)(rowb + i) << 6;
            uint2 o = make_uint2(pk2bf(acc0[i] * sc, acc1[i] * sc),
                                 pk2bf(acc2[i] * sc, acc3[i] * sc));
            *(uint2*)(Hs1 + ro + (colb << 2)) = o;
        }
    }
}

#define ACC8(H, W) \
    a0 = fmaf(bflo(H.x), W, a0); a1 = fmaf(bfhi(H.x), W, a1); \
    a2 = fmaf(bflo(H.y), W, a2); a3 = fmaf(bfhi(H.y), W, a3); \
    a4 = fmaf(bflo(H.z), W, a4); a5 = fmaf(bfhi(H.z), W, a5); \
    a6 = fmaf(bflo(H.w), W, a6); a7 = fmaf(bfhi(H.w), W, a7);

#define GROW(s) (*(const uint4*)(Hs + ((unsigned)(s) << 6) + (h8 << 3)))

#define HALF(hX0, hX1, hX2, hX3, sX0, sX1, sX2, sX3, wX0, wX1, wX2, wX3)  \
    {                                                                     \
        int jn = j + 8;                                                   \
        int n0 = sX0, n1 = sX1, n2 = sX2, n3 = sX3;                       \
        float v0 = 0.f, v1 = 0.f, v2 = 0.f, v3 = 0.f;                     \
        if (jn     < end) { n0 = esrc[jn];     v0 = 1.f; }                \
        if (jn + 1 < end) { n1 = esrc[jn + 1]; v1 = 1.f; }                \
        if (jn + 2 < end) { n2 = esrc[jn + 2]; v2 = 1.f; }                \
        if (jn + 3 < end) { n3 = esrc[jn + 3]; v3 = 1.f; }                \
        ACC8(hX0, wX0) ACC8(hX1, wX1) ACC8(hX2, wX2) ACC8(hX3, wX3)       \
        hX0 = GROW(n0); hX1 = GROW(n1); hX2 = GROW(n2); hX3 = GROW(n3);   \
        sX0 = n0; sX1 = n1; sX2 = n2; sX3 = n3;                           \
        wX0 = v0; wX1 = v1; wX2 = v2; wX3 = v3;                           \
        j += 4;                                                           \
    }

// ---- FUSED aggregation + GEMM.
// Block = 32 CONSECUTIVE degree-sorted slots of bucket q, degree-band
// L = 15 - blk/NB (heavy-first LPT dispatch). All 4 waves sit in the same
// degree band -> minimal max-over-waves barrier waste. Phase 1: 8 slots/
// wave x 8 lanes, 2-deep ping-pong gather pipeline, weight-0 fmaf masking,
// register accumulation. Phase 2: LDS transpose (XOR swizzle) -> 4 MFMAs/
// wave; bf16 (*pdinv) or fp32 (+bias2) output scattered via perm.
template <bool RELU, bool OUT_F32>
__global__ void __launch_bounds__(256)
k_fagg(const int* __restrict__ perm, const int2* __restrict__ pofs,
       const float* __restrict__ pdinv, const int* __restrict__ esrc,
       const unsigned short* __restrict__ Hs, const float* __restrict__ bias1,
       const unsigned short* __restrict__ Wpk, const float* __restrict__ bias2,
       void* __restrict__ outv, int nbuck, int n) {
    __shared__ uint4 lds_a[32][8];
    int tid = threadIdx.x;
    int lane = tid & 63;
    int wv = tid >> 6;
    int h8 = lane & 7;
    int q = blockIdx.x % nbuck;                  // bucket
    int L = 15 - blockIdx.x / nbuck;             // degree band, heavy first
    int sbase = (q << 9) + (L << 5);
    int rl = (wv << 3) + (lane >> 3);            // local row 0..31
    int slot = sbase + rl;
    bool ok = slot < n;
    int node = 0, beg = 0, end = 0;
    float dd = 0.f;
    if (ok) {
        node = perm[slot];
        int2 oe = pofs[slot];
        beg = oe.x; end = oe.y;
        dd = pdinv[slot];
    }
    float a0 = 0.f, a1 = 0.f, a2 = 0.f, a3 = 0.f, a4 = 0.f, a5 = 0.f, a6 = 0.f, a7 = 0.f;
    {
        int j = beg;
        int sA0 = 0, sA1 = 0, sA2 = 0, sA3 = 0;
        float wA0 = 0.f, wA1 = 0.f, wA2 = 0.f, wA3 = 0.f;
        if (j     < end) { sA0 = esrc[j];     wA0 = 1.f; }
        if (j + 1 < end) { sA1 = esrc[j + 1]; wA1 = 1.f; }
        if (j + 2 < end) { sA2 = esrc[j + 2]; wA2 = 1.f; }
        if (j + 3 < end) { sA3 = esrc[j + 3]; wA3 = 1.f; }
        int sB0 = sA0, sB1 = sA1, sB2 = sA2, sB3 = sA3;
        float wB0 = 0.f, wB1 = 0.f, wB2 = 0.f, wB3 = 0.f;
        if (j + 4 < end) { sB0 = esrc[j + 4]; wB0 = 1.f; }
        if (j + 5 < end) { sB1 = esrc[j + 5]; wB1 = 1.f; }
        if (j + 6 < end) { sB2 = esrc[j + 6]; wB2 = 1.f; }
        if (j + 7 < end) { sB3 = esrc[j + 7]; wB3 = 1.f; }
        uint4 hA0 = GROW(sA0), hA1 = GROW(sA1), hA2 = GROW(sA2), hA3 = GROW(sA3);
        uint4 hB0 = GROW(sB0), hB1 = GROW(sB1), hB2 = GROW(sB2), hB3 = GROW(sB3);
        while (__ballot(j < end)) {
            HALF(hA0, hA1, hA2, hA3, sA0, sA1, sA2, sA3, wA0, wA1, wA2, wA3)
            if (!__ballot(j < end)) break;
            HALF(hB0, hB1, hB2, hB3, sB0, sB1, sB2, sB3, wB0, wB1, wB2, wB3)
        }
    }
    uint4 packed = make_uint4(0, 0, 0, 0);
    if (ok) {
        uint4 sv = *(const uint4*)(Hs + ((unsigned)node << 6) + (h8 << 3));
        const float4* b4 = (const float4*)bias1;
        float4 bA = b4[h8 * 2], bB = b4[h8 * 2 + 1];
        float r0 = (a0 + bflo(sv.x)) * dd + bA.x;
        float r1 = (a1 + bfhi(sv.x)) * dd + bA.y;
        float r2 = (a2 + bflo(sv.y)) * dd + bA.z;
        float r3 = (a3 + bfhi(sv.y)) * dd + bA.w;
        float r4 = (a4 + bflo(sv.z)) * dd + bB.x;
        float r5 = (a5 + bfhi(sv.z)) * dd + bB.y;
        float r6 = (a6 + bflo(sv.w)) * dd + bB.z;
        float r7 = (a7 + bfhi(sv.w)) * dd + bB.w;
        if (RELU) {
            r0 = fmaxf(r0, 0.f); r1 = fmaxf(r1, 0.f); r2 = fmaxf(r2, 0.f); r3 = fmaxf(r3, 0.f);
            r4 = fmaxf(r4, 0.f); r5 = fmaxf(r5, 0.f); r6 = fmaxf(r6, 0.f); r7 = fmaxf(r7, 0.f);
        }
        packed = make_uint4(pk2bf(r0, r1), pk2bf(r2, r3), pk2bf(r4, r5), pk2bf(r6, r7));
    }
    lds_a[rl][h8 ^ (rl & 7)] = packed;          // XOR swizzle: banks spread
    __syncthreads();
    // ---- phase 2: GEMM on the block's 32 rows ----
    int hh = wv & 1, tt = wv >> 1;
    BF8 bq0, bq1, bq2, bq3;
    {
        const uint4* wp = (const uint4*)Wpk;
        bq0.q = wp[(4 * hh + 0) * 64 + lane];
        bq1.q = wp[(4 * hh + 1) * 64 + lane];
        bq2.q = wp[(4 * hh + 2) * 64 + lane];
        bq3.q = wp[(4 * hh + 3) * 64 + lane];
    }
    int mr = lane & 15, kq = lane >> 4, colb = lane & 15;
    int rloc = tt * 16 + mr;
    BF8 fa0, fa1;
    fa0.q = lds_a[rloc][kq ^ (rloc & 7)];
    fa1.q = lds_a[rloc][(kq + 4) ^ (rloc & 7)];
    f32x4 accA = {0.f, 0.f, 0.f, 0.f}, accB = accA;
    accA = __builtin_amdgcn_mfma_f32_16x16x32_bf16(fa0.v, bq0.v, accA, 0, 0, 0);
    accA = __builtin_amdgcn_mfma_f32_16x16x32_bf16(fa1.v, bq1.v, accA, 0, 0, 0);
    accB = __builtin_amdgcn_mfma_f32_16x16x32_bf16(fa0.v, bq2.v, accB, 0, 0, 0);
    accB = __builtin_amdgcn_mfma_f32_16x16x32_bf16(fa1.v, bq3.v, accB, 0, 0, 0);
    float b2x = 0.f, b2y = 0.f;
    if (OUT_F32) {
        b2x = bias2[(colb << 2) + (hh << 1)];
        b2y = bias2[(colb << 2) + (hh << 1) + 1];
    }
    int rowb = tt * 16 + (kq << 2);
#pragma unroll
    for (int i = 0; i < 4; ++i) {
        int sl = sbase + rowb + i;
        if (sl >= n) continue;
        int orow = perm[sl];
        if (OUT_F32) {
            float2 o = make_float2(accA[i] + b2x, accB[i] + b2y);
            *(float2*)((float*)outv + ((unsigned)orow << 6) + (colb << 2) + (hh << 1)) = o;
        } else {
            float sc = pdinv[sl];
            unsigned o = pk2bf(accA[i] * sc, accB[i] * sc);
            *(unsigned*)((unsigned short*)outv + ((unsigned)orow << 6) + (colb << 2) + (hh << 1)) = o;
        }
    }
}

extern "C" void kernel_launch(void* const* d_in, const int* in_sizes, int n_in,
                              void* d_out, int out_size, void* d_ws, size_t ws_size,
                              hipStream_t stream) {
    const float* x  = (const float*)d_in[0];
    const int*   ei = (const int*)d_in[1];   // [2][E] int32
    const float* W1 = (const float*)d_in[2];
    const float* b1 = (const float*)d_in[3];
    const float* W2 = (const float*)d_in[4];
    const float* b2 = (const float*)d_in[5];
    const float* Wl = (const float*)d_in[6];
    const float* bl = (const float*)d_in[7];
    float* out = (float*)d_out;

    const int n = in_sizes[0] / FEAT;   // 100000
    const int E = in_sizes[1] / 2;      // 1200000
    const int* src = ei;
    const int* dst = ei + E;

    const int B = 256;
    const int NB = (n + 511) >> 9;            // 196 buckets
    const int pblocks = (E + 4095) / 4096;
    const int fagg_blocks = NB * 16;          // 16 degree-bands x 32 slots per bucket

    char* w = (char*)d_ws;
    int*   bcnt     = (int*)w;              w += 256 * 4;
    float* pdinv    = (float*)w;            w += (size_t)n * 4;
    int*   perm     = (int*)w;              w += (size_t)n * 4;
    w = (char*)(((uintptr_t)w + 15) & ~(uintptr_t)15);
    int2*  pofs     = (int2*)w;             w += (size_t)n * 8;
    unsigned short* Wpk = (unsigned short*)w;  w += 3 * 4096 * 2;
    w = (char*)(((uintptr_t)w + 15) & ~(uintptr_t)15);
    unsigned* buckets = (unsigned*)w;       w += (size_t)NB * CAP * 4;
    int*   esrc     = (int*)w;              w += (size_t)NB * CAP * 4;
    unsigned short* bufA = (unsigned short*)w;  w += (size_t)n * FEAT * 2;  // Hs1
    unsigned short* bufB = (unsigned short*)w;                              // Hs3

    // ---- CSR build + fused layer-1 GEMM ----
    hipMemsetAsync(bcnt, 0, 256 * 4, stream);
    k_part<<<dim3(pblocks + 3), dim3(B), 0, stream>>>(src, dst, bcnt, buckets, E,
                                                      pblocks, W1, W2, Wl, Wpk);
    k_csr<<<dim3(NB), dim3(512), 0, stream>>>(buckets, bcnt, x, Wpk, bufA,
                                              esrc, perm, pofs, pdinv, n);

    // ---- fused layer-1 agg + layer-2 GEMM: Hs3 = (relu(agg(Hs1)+b1)@W2)*dinv ----
    k_fagg<true, false><<<dim3(fagg_blocks), dim3(B), 0, stream>>>(
        perm, pofs, pdinv, esrc, bufA, b1, Wpk + 4096, nullptr, bufB, NB, n);

    // ---- fused layer-2 agg + final linear: out = (agg(Hs3)+b2)@Wl + bl ----
    k_fagg<false, true><<<dim3(fagg_blocks), dim3(B), 0, stream>>>(
        perm, pofs, pdinv, esrc, bufB, b2, Wpk + 8192, bl, out, NB, n);
}